// Round 22
// baseline (165.032 us; speedup 1.0000x reference)
//
#include <hip/hip_runtime.h>
#include <hip/hip_bf16.h>

// Shapes: B=2, H=W=64, HW=4096, DIM=32, HID=128
#define HWSZ 4096

typedef _Float16 half8 __attribute__((ext_vector_type(8)));
typedef _Float16 half4 __attribute__((ext_vector_type(4)));
typedef float f32x4 __attribute__((ext_vector_type(4)));

__device__ __forceinline__ float gelu_f(float v) {
    return 0.5f * v * (1.0f + erff(v * 0.7071067811865475f));
}

// ---------------- KPREP: all weight transforms + FULL cl zero-fill (range ladder)
__device__ __forceinline__ void wtr_elem(const float* __restrict__ w,
                                         _Float16* __restrict__ o,
                                         int i, int T, int Op, int O, float scale) {
    int c = i & 127;
    int op = (i >> 7) % Op;
    int t = i / (128 * Op);
    float v = (op < O) ? w[((size_t)(op * 128 + c)) * T + t] * scale : 0.f;
    o[i] = (_Float16)v;
}

// fragment-ordered weights: o[((t*MTt+m)*4+cc)*512 + l*8 + j] = w[oc=m*16+(l&15)][ch=(l>>4)*8+cc*32+j][t]*scale
__device__ __forceinline__ void wfrag_elemO(const float* __restrict__ w,
                                            _Float16* __restrict__ o,
                                            int i, int T, int MTt, int O, float scale) {
    int j = i & 7;
    int l = (i >> 3) & 63;
    int cc = (i >> 9) & 3;
    int m = (i >> 11) % MTt;
    int t = i / (2048 * MTt);
    int oc = m * 16 + (l & 15);
    int ch = (l >> 4) * 8 + cc * 32 + j;
    float v = (oc < O) ? w[((size_t)(oc * 128 + ch)) * T + t] * scale : 0.f;
    o[i] = (_Float16)v;
}

__global__ __launch_bounds__(256) void kprep(const float* __restrict__ dww,
                                             const float* __restrict__ pww,
                                             const float* __restrict__ o3w,
                                             const float* __restrict__ d3w,
                                             const float* __restrict__ o4w,
                                             const float* __restrict__ d4w,
                                             const float* __restrict__ o5w,
                                             const float* __restrict__ d5w,
                                             const float* __restrict__ w1,
                                             _Float16* __restrict__ dwt,
                                             _Float16* __restrict__ pwt,
                                             _Float16* __restrict__ wA3,
                                             _Float16* __restrict__ wA4,
                                             _Float16* __restrict__ wA5,
                                             _Float16* __restrict__ wM3,
                                             _Float16* __restrict__ wM4,
                                             _Float16* __restrict__ wM5,
                                             _Float16* __restrict__ wA1,
                                             unsigned int* __restrict__ zbase) {
    int i = blockIdx.x * 256 + threadIdx.x;
    if (i < 1152) {
        int c = i & 127, j = i >> 7;
        dwt[j * 128 + c] = (_Float16)dww[c * 9 + j];
        return;
    }
    i -= 1152;
    if (i < 32768) { pwt[i] = (_Float16)pww[i]; return; }
    i -= 32768;
    if (i < 802816) { wfrag_elemO(o3w, wA3, i, 49, 8, 98, 256.f); return; }
    i -= 802816;
    if (i < 36864) { wfrag_elemO(o4w, wA4, i, 9, 2, 18, 256.f); return; }
    i -= 36864;
    if (i < 204800) { wfrag_elemO(o5w, wA5, i, 25, 4, 50, 256.f); return; }
    i -= 204800;
    if (i < 802816) { wfrag_elemO(d3w, wM3, i, 49, 8, 128, 16.f); return; }
    i -= 802816;
    if (i < 147456) { wfrag_elemO(d4w, wM4, i, 9, 8, 128, 16.f); return; }
    i -= 147456;
    if (i < 409600) { wfrag_elemO(d5w, wM5, i, 25, 8, 128, 16.f); return; }
    i -= 409600;
    if (i < 4096) {  // wA1[oc*32+k] = w1[k*128+oc] for k1G
        int k = i & 31, oc = i >> 5;
        wA1[i] = (_Float16)w1[k * 128 + oc];
        return;
    }
    i -= 4096;
    if (i < 1290240) { zbase[i] = 0u; return; }
}

// ---------------- K1G: x(B,HW,32) @ w1 + b1, gelu -> CL f16 (MFMA, K=32)
__global__ __launch_bounds__(512) void k1G(const float* __restrict__ x,
                                           const _Float16* __restrict__ wA1,
                                           const float* __restrict__ b1,
                                           _Float16* __restrict__ xicl) {
    int tid = threadIdx.x;
    int wv = tid >> 6;
    int l = tid & 63;
    int col = l & 15, kg = l >> 4;
    int blk = blockIdx.x;  // 512: b = blk>>8, 16 px
    int b = blk >> 8;
    int p = ((blk & 255) << 4) + col;
    const float* xr = x + ((size_t)(b * HWSZ) + p) * 32 + kg * 8;
    half8 bf;
#pragma unroll
    for (int j = 0; j < 8; ++j) bf[j] = (_Float16)xr[j];
    half8 af = *(const half8*)(wA1 + (wv * 16 + col) * 32 + kg * 8);
    f32x4 acc = (f32x4){0.f, 0.f, 0.f, 0.f};
    acc = __builtin_amdgcn_mfma_f32_16x16x32_f16(af, bf, acc, 0, 0, 0);
    half4 t4;
#pragma unroll
    for (int r = 0; r < 4; ++r) {
        int oc = wv * 16 + kg * 4 + r;
        t4[r] = (_Float16)gelu_f(acc[r] + b1[oc]);
    }
    *(half4*)(xicl + ((size_t)(b * HWSZ) + p) * 128 + wv * 16 + kg * 4) = t4;
}

// ---------------- K2: depthwise 3x3 (pad 1) + bias, CL f16 in/out
__global__ __launch_bounds__(256) void k2_cl(const _Float16* __restrict__ xicl,
                                             const _Float16* __restrict__ dwt,
                                             const float* __restrict__ dwb,
                                             _Float16* __restrict__ dcl) {
    int idx = blockIdx.x * 256 + threadIdx.x;  // (b,p,cg)
    int cg = idx & 15;
    int p = (idx >> 4) & 4095;
    int b = idx >> 16;
    int h = p >> 6, w = p & 63;
    const _Float16* base = xicl + (size_t)b * HWSZ * 128;
    float acc[8];
#pragma unroll
    for (int j = 0; j < 8; ++j) acc[j] = 0.f;
#pragma unroll
    for (int i = 0; i < 3; ++i) {
        int y = h + i - 1;
        if ((unsigned)y > 63u) continue;
#pragma unroll
        for (int j2 = 0; j2 < 3; ++j2) {
            int xx = w + j2 - 1;
            if ((unsigned)xx > 63u) continue;
            half8 v = *(const half8*)(base + ((size_t)(y * 64 + xx)) * 128 + cg * 8);
            half8 wv8 = *(const half8*)(dwt + (i * 3 + j2) * 128 + cg * 8);
#pragma unroll
            for (int j = 0; j < 8; ++j) acc[j] = fmaf((float)v[j], (float)wv8[j], acc[j]);
        }
    }
    half8 o;
#pragma unroll
    for (int j = 0; j < 8; ++j) o[j] = (_Float16)(acc[j] + dwb[cg * 8 + j]);
    *(half8*)(dcl + ((size_t)(b * HWSZ) + p) * 128 + cg * 8) = o;
}

// ---------------- K3G: pointwise 128->256 MFMA GEMM + bias + gelu
__global__ __launch_bounds__(512) void k3G(const _Float16* __restrict__ dcl,
                                           const _Float16* __restrict__ pwt,
                                           const float* __restrict__ pwb,
                                           _Float16* __restrict__ clA,
                                           _Float16* __restrict__ gcl) {
    int tid = threadIdx.x;
    int wv = tid >> 6;
    int l = tid & 63;
    int col = l & 15, kg = l >> 4;
    int blk = blockIdx.x;
    int hf = blockIdx.y;  // 0:a 1:g
    int b = blk >> 8;
    int px0 = (blk & 255) << 4;
    int p = px0 + col;
    const _Float16* bp = dcl + ((size_t)(b * HWSZ) + p) * 128 + kg * 8;
    int oc0 = hf * 128 + wv * 16;
    const _Float16* ap = pwt + (size_t)(oc0 + col) * 128 + kg * 8;
    f32x4 acc = (f32x4){0.f, 0.f, 0.f, 0.f};
#pragma unroll
    for (int cc = 0; cc < 4; ++cc) {
        half8 bf = *(const half8*)(bp + cc * 32);
        half8 af = *(const half8*)(ap + cc * 32);
        acc = __builtin_amdgcn_mfma_f32_16x16x32_f16(af, bf, acc, 0, 0, 0);
    }
    int h = p >> 6, w = p & 63;
    half4 t4;
#pragma unroll
    for (int r = 0; r < 4; ++r) {
        int oc = oc0 + kg * 4 + r;
        t4[r] = (_Float16)gelu_f(acc[r] + pwb[oc]);
    }
    if (hf == 0) {
        _Float16* dst = clA + (size_t)b * 70 * 72 * 128 +
                        ((size_t)(h + 3) * 72 + (w + 3)) * 128 + wv * 16 + kg * 4;
        *(half4*)dst = t4;
    } else {
        *(half4*)(gcl + ((size_t)(b * HWSZ) + p) * 128 + wv * 16 + kg * 4) = t4;
    }
}

// ---------------- K4Gv4: offset conv GEMM with LDS-staged B + fragment-ordered weights
template <int KK, int PAD, int T, int MT, int NG, int NA, int WPX>
__global__ __launch_bounds__(512) void k4Gv4(const _Float16* __restrict__ cl,
                                             const _Float16* __restrict__ wA,
                                             const float* __restrict__ obias,
                                             float* __restrict__ offb, int OC) {
    constexpr int OCp = MT * 16;
    constexpr int COLS = WPX + KK - 1;
    constexpr int NB = 64 / WPX;
    __shared__ _Float16 bS[KK * COLS * 128];

    int tid = threadIdx.x;
    int blk = blockIdx.x;
    int w0 = (blk % NB) * WPX;
    int h = (blk / NB) & 63;
    int b = blk / (NB * 64);
    const _Float16* clb = cl + (size_t)b * 70 * 72 * 128;

    int hh0 = h + (3 - PAD);
    int ww0 = w0 + (3 - PAD);
    for (int g = tid; g < KK * COLS * 16; g += 512) {
        int r = g / (COLS * 16);
        int rest = g - r * (COLS * 16);
        int c = rest >> 4;
        int s = rest & 15;
        half8 v = *(const half8*)(clb + ((size_t)(hh0 + r) * 72 + (ww0 + c)) * 128 + s * 8);
        *(half8*)&bS[((r * COLS + c) * 16 + (s ^ (c & 7))) * 8] = v;
    }

    int wv = tid >> 6;
    int l = tid & 63;
    int col = l & 15, kg = l >> 4;
    int m = wv % MT;
    int ng = wv / MT;

    const half8* apb = (const half8*)wA + (size_t)m * 4 * 64 + l;
    half8 afv[4];
#pragma unroll
    for (int cc = 0; cc < 4; ++cc) afv[cc] = apb[cc * 64];

    f32x4 acc[NA];
#pragma unroll
    for (int a = 0; a < NA; ++a) acc[a] = (f32x4){0.f, 0.f, 0.f, 0.f};

    __syncthreads();

    for (int t = 0; t < T; ++t) {
        int ky = t / KK, kx = t - ky * KK;
        half8 afn[4];
        if (t + 1 < T) {
            const half8* apn = apb + (size_t)(t + 1) * MT * 4 * 64;
#pragma unroll
            for (int cc = 0; cc < 4; ++cc) afn[cc] = apn[cc * 64];
        }
#pragma unroll
        for (int a = 0; a < NA; ++a) {
            int cw = ng * NA * 16 + a * 16 + col + kx;
#pragma unroll
            for (int cc = 0; cc < 4; ++cc) {
                half8 bf = *(const half8*)&bS[((ky * COLS + cw) * 16 + ((cc * 4 + kg) ^ (cw & 7))) * 8];
                acc[a] = __builtin_amdgcn_mfma_f32_16x16x32_f16(afv[cc], bf, acc[a], 0, 0, 0);
            }
        }
#pragma unroll
        for (int cc = 0; cc < 4; ++cc) afv[cc] = afn[cc];
    }

#pragma unroll
    for (int a = 0; a < NA; ++a) {
        int px = h * 64 + w0 + ng * NA * 16 + a * 16 + col;
#pragma unroll
        for (int r = 0; r < 4; ++r) {
            int oc = m * 16 + kg * 4 + r;
            float v = acc[a][r] * (1.0f / 256.0f) + (oc < OC ? obias[oc] : 0.f);
            offb[((size_t)(b * OCp + oc)) * HWSZ + px] = v;
        }
    }
}

// ---------------- K5Gv14: v13 with packed-f16 BLEND (v_pk_fma_f16 path)
// Static LDS window + LDS params (pw f32, po uchar4) + fragment-ordered weights.
// grid 512; OUTMODE 0 = padded CL write, 2 = flat CL.
template <int KK, int PAD, int T, int OUTMODE>
__global__ __launch_bounds__(512, 4) void k5Gv14(const _Float16* __restrict__ cl,
                                                 const float* __restrict__ offb, int OFFP,
                                                 const _Float16* __restrict__ wM,
                                                 const float* __restrict__ bias,
                                                 _Float16* __restrict__ outH) {
    constexpr int ROWS = KK + 2;
    constexpr int COLSW = KK + 17;
    constexpr int UMAX = T * 16;
    __shared__ _Float16 win[ROWS * COLSW * 128];
    __shared__ _Float16 panel[2][16][128];
    __shared__ float pw4[4][UMAX];
    __shared__ uchar4 po4[UMAX];

    int tid = threadIdx.x;
    int blk = blockIdx.x;   // 512: b = blk>>8, 16 px
    int b = blk >> 8;
    int px0 = (blk & 255) << 4;
    int h0 = px0 >> 6;
    int w0 = px0 & 63;
    const _Float16* clb = cl + (size_t)b * 70 * 72 * 128;
    const float* ob = offb + (size_t)b * OFFP * HWSZ;

    int R0 = min(max(h0 - PAD + 2, 0), 68 - KK);
    int C0 = min(max(w0 - PAD + 2, 0), 55 - KK);

    // ---- stage window ONCE (coalesced)
    for (int g = tid; g < ROWS * COLSW * 16; g += 512) {
        int r = g / (COLSW * 16);
        int rest = g - r * (COLSW * 16);
        int c = rest >> 4, s = rest & 15;
        *(half8*)&win[((r * COLSW + c) << 7) + s * 8] =
            *(const half8*)(clb + ((size_t)(R0 + r) * 72 + (C0 + c)) * 128 + s * 8);
    }

    // ---- precompute bilinear params ONCE per (tap, pixel)
    for (int q = tid; q < T * 16; q += 512) {
        int t = q >> 4;
        int px = q & 15;
        int p_s = px0 + px;
        int w_s = w0 + px;
        int ky = t / KK, kx = t - ky * KK;
        float dy = ob[(size_t)(2 * t) * HWSZ + p_s];
        float dx = ob[(size_t)(2 * t + 1) * HWSZ + p_s];
        float py = (float)(h0 + ky - PAD) + dy;
        float pxs = (float)(w_s + kx - PAD) + dx;
        float y0f = floorf(py), x0f = floorf(pxs);
        float wy = py - y0f, wx = pxs - x0f;
        int y0 = (int)y0f, x0 = (int)x0f;
        int y1 = y0 + 1, x1 = x0 + 1;
        bool vy0 = (y0 >= 0) && (y0 < 64), vy1 = (y1 >= 0) && (y1 < 64);
        bool vx0 = (x0 >= 0) && (x0 < 64), vx1 = (x1 >= 0) && (x1 < 64);
        int cy0 = min(max(y0, 0), 63) + 3, cy1 = min(max(y1, 0), 63) + 3;
        int cx0 = min(max(x0, 0), 63) + 3, cx1 = min(max(x1, 0), 63) + 3;
        pw4[0][q] = (vy0 && vx0) ? (1.f - wy) * (1.f - wx) : 0.f;
        pw4[1][q] = (vy0 && vx1) ? (1.f - wy) * wx : 0.f;
        pw4[2][q] = (vy1 && vx0) ? wy * (1.f - wx) : 0.f;
        pw4[3][q] = (vy1 && vx1) ? wy * wx : 0.f;
        po4[q] = make_uchar4((unsigned char)(cy0 - R0), (unsigned char)(cy1 - R0),
                             (unsigned char)(cx0 - C0), (unsigned char)(cx1 - C0));
    }

    // sampling roles: thread = (pixel, 4-channel slice)
    int px_s = tid >> 5;    // 0..15
    int slice4 = tid & 31;  // 4 channels each
    // MFMA roles
    int wv = tid >> 6;
    int l = tid & 63;
    int col = l & 15, kg = l >> 4;

    f32x4 acc = (f32x4){0.f, 0.f, 0.f, 0.f};
    half8 wA8[4], wB8[4];

    auto BLEND = [&](int t, int buf) {
        int q = t * 16 + px_s;
        _Float16 w00 = (_Float16)pw4[0][q], w01 = (_Float16)pw4[1][q];
        _Float16 w10 = (_Float16)pw4[2][q], w11 = (_Float16)pw4[3][q];
        uchar4 pk = po4[q];
        int o0 = ((int)pk.x * COLSW) << 7;
        int o1 = ((int)pk.y * COLSW) << 7;
        int o2 = ((int)pk.z) << 7;
        int o3 = ((int)pk.w) << 7;
        int c0 = slice4 * 4;
        half4 a00 = *(const half4*)(win + o0 + o2 + c0);
        half4 a01 = *(const half4*)(win + o0 + o3 + c0);
        half4 a10 = *(const half4*)(win + o1 + o2 + c0);
        half4 a11 = *(const half4*)(win + o1 + o3 + c0);
        half4 r = a00 * w00 + a01 * w01 + a10 * w10 + a11 * w11;  // packed f16 fma
        *(half4*)&panel[buf][px_s][((slice4 >> 1) ^ (px_s & 7)) * 8 + (slice4 & 1) * 4] = r;
    };
    auto LOADW = [&](half8* w8, int t) {
        const half8* ap = (const half8*)wM + ((size_t)(t * 8 + wv) * 4) * 64 + l;
#pragma unroll
        for (int cc = 0; cc < 4; ++cc) w8[cc] = ap[cc * 64];
    };
    auto MM = [&](const half8* w8, int buf) {
#pragma unroll
        for (int cc = 0; cc < 4; ++cc) {
            half8 bf = *(const half8*)&panel[buf][col][((cc * 4 + kg) ^ (col & 7)) * 8];
            acc = __builtin_amdgcn_mfma_f32_16x16x32_f16(w8[cc], bf, acc, 0, 0, 0);
        }
    };
    auto BAR = [&]() {
        asm volatile("s_waitcnt lgkmcnt(0)" ::: "memory");
        __builtin_amdgcn_s_barrier();
        __builtin_amdgcn_sched_barrier(0);
    };

    // ---- prologue
    LOADW(wA8, 0);
    if (1 < T) LOADW(wB8, 1);
    BAR();  // window + params staged
    BLEND(0, 0);
    BAR();  // panel[0] ready

    for (int t = 0; t < T; t += 2) {
        MM(wA8, t & 1);
        if (t + 2 < T) LOADW(wA8, t + 2);
        if (t + 1 < T) BLEND(t + 1, (t + 1) & 1);
        BAR();
        if (t + 1 < T) {
            MM(wB8, (t + 1) & 1);
            if (t + 3 < T) LOADW(wB8, t + 3);
            if (t + 2 < T) BLEND(t + 2, (t + 2) & 1);
            BAR();
        }
    }

    // ---- fused epilogue: bias + gelu -> f16 CL
    int p = px0 + col;
    half4 t4;
#pragma unroll
    for (int r = 0; r < 4; ++r) {
        int oc = wv * 16 + kg * 4 + r;
        t4[r] = (_Float16)gelu_f(acc[r] * (1.0f / 16.0f) + bias[oc]);
    }
    if (OUTMODE == 0) {
        int h = p >> 6, w = p & 63;
        _Float16* dst = outH + (size_t)b * 70 * 72 * 128 +
                        ((size_t)(h + 3) * 72 + (3 + w)) * 128 + wv * 16 + kg * 4;
        *(half4*)dst = t4;
    } else {
        *(half4*)(outH + ((size_t)(b * HWSZ) + p) * 128 + wv * 16 + kg * 4) = t4;
    }
}

// ---------------- K6Z: z = gelu(a)*g fused with out = z @ w2 + b2
__global__ __launch_bounds__(256) void k6z(const _Float16* __restrict__ a5cl,
                                           const _Float16* __restrict__ gcl,
                                           const float* __restrict__ w2,
                                           const float* __restrict__ b2,
                                           float* __restrict__ out) {
    __shared__ float zs[16][128];
    int tid = threadIdx.x;
    int blk = blockIdx.x;  // 512: (b, 16-px group)
    int b = blk >> 8;
    int px0 = (blk & 255) << 4;
    int px = tid >> 4, sl = tid & 15;
    size_t rb = ((size_t)(b * HWSZ) + px0 + px) * 128 + sl * 8;
    half8 a = *(const half8*)(a5cl + rb);
    half8 g = *(const half8*)(gcl + rb);
#pragma unroll
    for (int j = 0; j < 8; ++j)
        zs[px][sl * 8 + j] = gelu_f((float)a[j]) * (float)g[j];
    __syncthreads();
    int d2 = (tid & 15) * 2;
    float acc0 = b2[d2], acc1 = b2[d2 + 1];
#pragma unroll 16
    for (int c = 0; c < 128; ++c) {
        float zv = zs[px][c];
        acc0 = fmaf(zv, w2[c * 32 + d2], acc0);
        acc1 = fmaf(zv, w2[c * 32 + d2 + 1], acc1);
    }
    float* o = out + ((size_t)(b * HWSZ) + px0 + px) * 32 + d2;
    o[0] = acc0;
    o[1] = acc1;
}

extern "C" void kernel_launch(void* const* d_in, const int* in_sizes, int n_in,
                              void* d_out, int out_size, void* d_ws, size_t ws_size,
                              hipStream_t stream) {
    const float* x   = (const float*)d_in[0];
    const float* w1  = (const float*)d_in[1];
    const float* b1  = (const float*)d_in[2];
    const float* dww = (const float*)d_in[3];
    const float* dwb = (const float*)d_in[4];
    const float* pww = (const float*)d_in[5];
    const float* pwb = (const float*)d_in[6];
    const float* o3w = (const float*)d_in[7];
    const float* o3b = (const float*)d_in[8];
    const float* d3w = (const float*)d_in[9];
    const float* d3b = (const float*)d_in[10];
    const float* o4w = (const float*)d_in[11];
    const float* o4b = (const float*)d_in[12];
    const float* d4w = (const float*)d_in[13];
    const float* d4b = (const float*)d_in[14];
    const float* o5w = (const float*)d_in[15];
    const float* o5b = (const float*)d_in[16];
    const float* d5w = (const float*)d_in[17];
    const float* d5b = (const float*)d_in[18];
    const float* w2  = (const float*)d_in[19];
    const float* b2  = (const float*)d_in[20];

    // ---- workspace map (float offsets) — unchanged
    float* ws = (float*)d_ws;
    float* offb = ws;                              // 1,048,576 fl
    _Float16* clA  = (_Float16*)(ws + 1048576);    // 645,120 fl (1,290,240 f16, B=2)
    _Float16* clB  = (_Float16*)(ws + 1693696);    // 645,120 fl (contiguous after clA)
    _Float16* xicl = (_Float16*)(ws + 2338816);    // 524,288 fl
    _Float16* dcl  = (_Float16*)(ws + 2863104);    // 524,288 fl
    _Float16* gcl  = (_Float16*)(ws + 3387392);    // 524,288 fl
    _Float16* a5cl = (_Float16*)(ws + 3911680);    // 524,288 fl
    _Float16* wA3  = (_Float16*)(ws + 4960256);    // 401,408 fl
    _Float16* wA4  = (_Float16*)(ws + 5361664);    // 18,432 fl
    _Float16* wA5  = (_Float16*)(ws + 5380096);    // 102,400 fl
    _Float16* wM3  = (_Float16*)(ws + 5482496);    // 401,408 fl
    _Float16* wM4  = (_Float16*)(ws + 5883904);    // 73,728 fl
    _Float16* wM5  = (_Float16*)(ws + 5957632);    // 102,400 fl
    _Float16* dwt  = (_Float16*)(ws + 6162432);    // 576 fl
    _Float16* pwt  = (_Float16*)(ws + 6163008);    // 16,384 fl
    _Float16* wA1  = (_Float16*)(ws + 9325120);    // 2,048 fl

    // prep
    kprep<<<14581, 256, 0, stream>>>(dww, pww, o3w, d3w, o4w, d4w, o5w, d5w, w1,
                                     dwt, pwt, wA3, wA4, wA5, wM3, wM4, wM5, wA1,
                                     (unsigned int*)clA);

    // front of net
    k1G<<<512, 512, 0, stream>>>(x, wA1, b1, xicl);
    k2_cl<<<512, 256, 0, stream>>>(xicl, dwt, dwb, dcl);
    k3G<<<dim3(512, 2), 512, 0, stream>>>(dcl, pwt, pwb, clA, gcl);

    // d3: k=7, pad=3, T=49  (k4 regridded: WPX=16 -> 512 blocks, MT=8, NG=1, NA=1)
    k4Gv4<7, 3, 49, 8, 1, 1, 16><<<512, 512, 0, stream>>>(clA, wA3, o3b, offb, 98);
    k5Gv14<7, 3, 49, 0><<<512, 512, 0, stream>>>(clA, offb, 128, wM3, d3b, clB);

    // d4: k=3, pad=1, T=9
    k4Gv4<3, 1, 9, 2, 4, 1, 64><<<128, 512, 0, stream>>>(clB, wA4, o4b, offb, 18);
    k5Gv14<3, 1, 9, 0><<<512, 512, 0, stream>>>(clB, offb, 32, wM4, d4b, clA);

    // d5: k=5, pad=2, T=25 -> flat CL f16
    k4Gv4<5, 2, 25, 4, 2, 1, 32><<<256, 512, 0, stream>>>(clA, wA5, o5b, offb, 50);
    k5Gv14<5, 2, 25, 2><<<512, 512, 0, stream>>>(clA, offb, 64, wM5, d5b, a5cl);

    // tail (fused)
    k6z<<<512, 256, 0, stream>>>(a5cl, gcl, w2, b2, (float*)d_out);
}

// Round 23
// 156.676 us; speedup vs baseline: 1.0533x; 1.0533x over previous
//
#include <hip/hip_runtime.h>
#include <hip/hip_bf16.h>

// Shapes: B=2, H=W=64, HW=4096, DIM=32, HID=128
#define HWSZ 4096

typedef _Float16 half8 __attribute__((ext_vector_type(8)));
typedef _Float16 half4 __attribute__((ext_vector_type(4)));
typedef float f32x4 __attribute__((ext_vector_type(4)));

__device__ __forceinline__ float gelu_f(float v) {
    return 0.5f * v * (1.0f + erff(v * 0.7071067811865475f));
}

// ---------------- KPREP: all weight transforms + FULL cl zero-fill (range ladder)
__device__ __forceinline__ void wtr_elem(const float* __restrict__ w,
                                         _Float16* __restrict__ o,
                                         int i, int T, int Op, int O, float scale) {
    int c = i & 127;
    int op = (i >> 7) % Op;
    int t = i / (128 * Op);
    float v = (op < O) ? w[((size_t)(op * 128 + c)) * T + t] * scale : 0.f;
    o[i] = (_Float16)v;
}

// fragment-ordered weights: o[((t*MTt+m)*4+cc)*512 + l*8 + j] = w[oc=m*16+(l&15)][ch=(l>>4)*8+cc*32+j][t]*scale
__device__ __forceinline__ void wfrag_elemO(const float* __restrict__ w,
                                            _Float16* __restrict__ o,
                                            int i, int T, int MTt, int O, float scale) {
    int j = i & 7;
    int l = (i >> 3) & 63;
    int cc = (i >> 9) & 3;
    int m = (i >> 11) % MTt;
    int t = i / (2048 * MTt);
    int oc = m * 16 + (l & 15);
    int ch = (l >> 4) * 8 + cc * 32 + j;
    float v = (oc < O) ? w[((size_t)(oc * 128 + ch)) * T + t] * scale : 0.f;
    o[i] = (_Float16)v;
}

__global__ __launch_bounds__(256) void kprep(const float* __restrict__ dww,
                                             const float* __restrict__ pww,
                                             const float* __restrict__ o3w,
                                             const float* __restrict__ d3w,
                                             const float* __restrict__ o4w,
                                             const float* __restrict__ d4w,
                                             const float* __restrict__ o5w,
                                             const float* __restrict__ d5w,
                                             const float* __restrict__ w1,
                                             _Float16* __restrict__ dwt,
                                             _Float16* __restrict__ pwt,
                                             _Float16* __restrict__ wA3,
                                             _Float16* __restrict__ wA4,
                                             _Float16* __restrict__ wA5,
                                             _Float16* __restrict__ wM3,
                                             _Float16* __restrict__ wM4,
                                             _Float16* __restrict__ wM5,
                                             _Float16* __restrict__ wA1,
                                             unsigned int* __restrict__ zbase) {
    int i = blockIdx.x * 256 + threadIdx.x;
    if (i < 1152) {
        int c = i & 127, j = i >> 7;
        dwt[j * 128 + c] = (_Float16)dww[c * 9 + j];
        return;
    }
    i -= 1152;
    if (i < 32768) { pwt[i] = (_Float16)pww[i]; return; }
    i -= 32768;
    if (i < 802816) { wfrag_elemO(o3w, wA3, i, 49, 8, 98, 256.f); return; }
    i -= 802816;
    if (i < 36864) { wfrag_elemO(o4w, wA4, i, 9, 2, 18, 256.f); return; }
    i -= 36864;
    if (i < 204800) { wfrag_elemO(o5w, wA5, i, 25, 4, 50, 256.f); return; }
    i -= 204800;
    if (i < 802816) { wfrag_elemO(d3w, wM3, i, 49, 8, 128, 16.f); return; }
    i -= 802816;
    if (i < 147456) { wfrag_elemO(d4w, wM4, i, 9, 8, 128, 16.f); return; }
    i -= 147456;
    if (i < 409600) { wfrag_elemO(d5w, wM5, i, 25, 8, 128, 16.f); return; }
    i -= 409600;
    if (i < 4096) {  // wA1[oc*32+k] = w1[k*128+oc] for k1G
        int k = i & 31, oc = i >> 5;
        wA1[i] = (_Float16)w1[k * 128 + oc];
        return;
    }
    i -= 4096;
    if (i < 1290240) { zbase[i] = 0u; return; }
}

// ---------------- K1G: x(B,HW,32) @ w1 + b1, gelu -> CL f16 (MFMA, K=32)
__global__ __launch_bounds__(512) void k1G(const float* __restrict__ x,
                                           const _Float16* __restrict__ wA1,
                                           const float* __restrict__ b1,
                                           _Float16* __restrict__ xicl) {
    int tid = threadIdx.x;
    int wv = tid >> 6;
    int l = tid & 63;
    int col = l & 15, kg = l >> 4;
    int blk = blockIdx.x;  // 512: b = blk>>8, 16 px
    int b = blk >> 8;
    int p = ((blk & 255) << 4) + col;
    const float* xr = x + ((size_t)(b * HWSZ) + p) * 32 + kg * 8;
    half8 bf;
#pragma unroll
    for (int j = 0; j < 8; ++j) bf[j] = (_Float16)xr[j];
    half8 af = *(const half8*)(wA1 + (wv * 16 + col) * 32 + kg * 8);
    f32x4 acc = (f32x4){0.f, 0.f, 0.f, 0.f};
    acc = __builtin_amdgcn_mfma_f32_16x16x32_f16(af, bf, acc, 0, 0, 0);
    half4 t4;
#pragma unroll
    for (int r = 0; r < 4; ++r) {
        int oc = wv * 16 + kg * 4 + r;
        t4[r] = (_Float16)gelu_f(acc[r] + b1[oc]);
    }
    *(half4*)(xicl + ((size_t)(b * HWSZ) + p) * 128 + wv * 16 + kg * 4) = t4;
}

// ---------------- K2: depthwise 3x3 (pad 1) + bias, CL f16 in/out
__global__ __launch_bounds__(256) void k2_cl(const _Float16* __restrict__ xicl,
                                             const _Float16* __restrict__ dwt,
                                             const float* __restrict__ dwb,
                                             _Float16* __restrict__ dcl) {
    int idx = blockIdx.x * 256 + threadIdx.x;  // (b,p,cg)
    int cg = idx & 15;
    int p = (idx >> 4) & 4095;
    int b = idx >> 16;
    int h = p >> 6, w = p & 63;
    const _Float16* base = xicl + (size_t)b * HWSZ * 128;
    float acc[8];
#pragma unroll
    for (int j = 0; j < 8; ++j) acc[j] = 0.f;
#pragma unroll
    for (int i = 0; i < 3; ++i) {
        int y = h + i - 1;
        if ((unsigned)y > 63u) continue;
#pragma unroll
        for (int j2 = 0; j2 < 3; ++j2) {
            int xx = w + j2 - 1;
            if ((unsigned)xx > 63u) continue;
            half8 v = *(const half8*)(base + ((size_t)(y * 64 + xx)) * 128 + cg * 8);
            half8 wv8 = *(const half8*)(dwt + (i * 3 + j2) * 128 + cg * 8);
#pragma unroll
            for (int j = 0; j < 8; ++j) acc[j] = fmaf((float)v[j], (float)wv8[j], acc[j]);
        }
    }
    half8 o;
#pragma unroll
    for (int j = 0; j < 8; ++j) o[j] = (_Float16)(acc[j] + dwb[cg * 8 + j]);
    *(half8*)(dcl + ((size_t)(b * HWSZ) + p) * 128 + cg * 8) = o;
}

// ---------------- K3G: pointwise 128->256 MFMA GEMM + bias + gelu
__global__ __launch_bounds__(512) void k3G(const _Float16* __restrict__ dcl,
                                           const _Float16* __restrict__ pwt,
                                           const float* __restrict__ pwb,
                                           _Float16* __restrict__ clA,
                                           _Float16* __restrict__ gcl) {
    int tid = threadIdx.x;
    int wv = tid >> 6;
    int l = tid & 63;
    int col = l & 15, kg = l >> 4;
    int blk = blockIdx.x;
    int hf = blockIdx.y;  // 0:a 1:g
    int b = blk >> 8;
    int px0 = (blk & 255) << 4;
    int p = px0 + col;
    const _Float16* bp = dcl + ((size_t)(b * HWSZ) + p) * 128 + kg * 8;
    int oc0 = hf * 128 + wv * 16;
    const _Float16* ap = pwt + (size_t)(oc0 + col) * 128 + kg * 8;
    f32x4 acc = (f32x4){0.f, 0.f, 0.f, 0.f};
#pragma unroll
    for (int cc = 0; cc < 4; ++cc) {
        half8 bf = *(const half8*)(bp + cc * 32);
        half8 af = *(const half8*)(ap + cc * 32);
        acc = __builtin_amdgcn_mfma_f32_16x16x32_f16(af, bf, acc, 0, 0, 0);
    }
    int h = p >> 6, w = p & 63;
    half4 t4;
#pragma unroll
    for (int r = 0; r < 4; ++r) {
        int oc = oc0 + kg * 4 + r;
        t4[r] = (_Float16)gelu_f(acc[r] + pwb[oc]);
    }
    if (hf == 0) {
        _Float16* dst = clA + (size_t)b * 70 * 72 * 128 +
                        ((size_t)(h + 3) * 72 + (w + 3)) * 128 + wv * 16 + kg * 4;
        *(half4*)dst = t4;
    } else {
        *(half4*)(gcl + ((size_t)(b * HWSZ) + p) * 128 + wv * 16 + kg * 4) = t4;
    }
}

// ---------------- K4Gv4: offset conv GEMM with LDS-staged B + fragment-ordered weights
template <int KK, int PAD, int T, int MT, int NG, int NA, int WPX>
__global__ __launch_bounds__(512) void k4Gv4(const _Float16* __restrict__ cl,
                                             const _Float16* __restrict__ wA,
                                             const float* __restrict__ obias,
                                             float* __restrict__ offb, int OC) {
    constexpr int OCp = MT * 16;
    constexpr int COLS = WPX + KK - 1;
    constexpr int NB = 64 / WPX;
    __shared__ _Float16 bS[KK * COLS * 128];

    int tid = threadIdx.x;
    int blk = blockIdx.x;
    int w0 = (blk % NB) * WPX;
    int h = (blk / NB) & 63;
    int b = blk / (NB * 64);
    const _Float16* clb = cl + (size_t)b * 70 * 72 * 128;

    int hh0 = h + (3 - PAD);
    int ww0 = w0 + (3 - PAD);
    for (int g = tid; g < KK * COLS * 16; g += 512) {
        int r = g / (COLS * 16);
        int rest = g - r * (COLS * 16);
        int c = rest >> 4;
        int s = rest & 15;
        half8 v = *(const half8*)(clb + ((size_t)(hh0 + r) * 72 + (ww0 + c)) * 128 + s * 8);
        *(half8*)&bS[((r * COLS + c) * 16 + (s ^ (c & 7))) * 8] = v;
    }

    int wv = tid >> 6;
    int l = tid & 63;
    int col = l & 15, kg = l >> 4;
    int m = wv % MT;
    int ng = wv / MT;

    const half8* apb = (const half8*)wA + (size_t)m * 4 * 64 + l;
    half8 afv[4];
#pragma unroll
    for (int cc = 0; cc < 4; ++cc) afv[cc] = apb[cc * 64];

    f32x4 acc[NA];
#pragma unroll
    for (int a = 0; a < NA; ++a) acc[a] = (f32x4){0.f, 0.f, 0.f, 0.f};

    __syncthreads();

    for (int t = 0; t < T; ++t) {
        int ky = t / KK, kx = t - ky * KK;
        half8 afn[4];
        if (t + 1 < T) {
            const half8* apn = apb + (size_t)(t + 1) * MT * 4 * 64;
#pragma unroll
            for (int cc = 0; cc < 4; ++cc) afn[cc] = apn[cc * 64];
        }
#pragma unroll
        for (int a = 0; a < NA; ++a) {
            int cw = ng * NA * 16 + a * 16 + col + kx;
#pragma unroll
            for (int cc = 0; cc < 4; ++cc) {
                half8 bf = *(const half8*)&bS[((ky * COLS + cw) * 16 + ((cc * 4 + kg) ^ (cw & 7))) * 8];
                acc[a] = __builtin_amdgcn_mfma_f32_16x16x32_f16(afv[cc], bf, acc[a], 0, 0, 0);
            }
        }
#pragma unroll
        for (int cc = 0; cc < 4; ++cc) afv[cc] = afn[cc];
    }

#pragma unroll
    for (int a = 0; a < NA; ++a) {
        int px = h * 64 + w0 + ng * NA * 16 + a * 16 + col;
#pragma unroll
        for (int r = 0; r < 4; ++r) {
            int oc = m * 16 + kg * 4 + r;
            float v = acc[a][r] * (1.0f / 256.0f) + (oc < OC ? obias[oc] : 0.f);
            offb[((size_t)(b * OCp + oc)) * HWSZ + px] = v;
        }
    }
}

// ---------------- K5Gv14: static LDS window + LDS params + packed-f16 BLEND
// grid 512; OUTMODE 0 = padded CL write, 2 = flat CL.
template <int KK, int PAD, int T, int OUTMODE>
__global__ __launch_bounds__(512, 4) void k5Gv14(const _Float16* __restrict__ cl,
                                                 const float* __restrict__ offb, int OFFP,
                                                 const _Float16* __restrict__ wM,
                                                 const float* __restrict__ bias,
                                                 _Float16* __restrict__ outH) {
    constexpr int ROWS = KK + 2;
    constexpr int COLSW = KK + 17;
    constexpr int UMAX = T * 16;
    __shared__ _Float16 win[ROWS * COLSW * 128];
    __shared__ _Float16 panel[2][16][128];
    __shared__ float pw4[4][UMAX];
    __shared__ uchar4 po4[UMAX];

    int tid = threadIdx.x;
    int blk = blockIdx.x;   // 512: b = blk>>8, 16 px
    int b = blk >> 8;
    int px0 = (blk & 255) << 4;
    int h0 = px0 >> 6;
    int w0 = px0 & 63;
    const _Float16* clb = cl + (size_t)b * 70 * 72 * 128;
    const float* ob = offb + (size_t)b * OFFP * HWSZ;

    int R0 = min(max(h0 - PAD + 2, 0), 68 - KK);
    int C0 = min(max(w0 - PAD + 2, 0), 55 - KK);

    // ---- stage window ONCE (coalesced)
    for (int g = tid; g < ROWS * COLSW * 16; g += 512) {
        int r = g / (COLSW * 16);
        int rest = g - r * (COLSW * 16);
        int c = rest >> 4, s = rest & 15;
        *(half8*)&win[((r * COLSW + c) << 7) + s * 8] =
            *(const half8*)(clb + ((size_t)(R0 + r) * 72 + (C0 + c)) * 128 + s * 8);
    }

    // ---- precompute bilinear params ONCE per (tap, pixel)
    for (int q = tid; q < T * 16; q += 512) {
        int t = q >> 4;
        int px = q & 15;
        int p_s = px0 + px;
        int w_s = w0 + px;
        int ky = t / KK, kx = t - ky * KK;
        float dy = ob[(size_t)(2 * t) * HWSZ + p_s];
        float dx = ob[(size_t)(2 * t + 1) * HWSZ + p_s];
        float py = (float)(h0 + ky - PAD) + dy;
        float pxs = (float)(w_s + kx - PAD) + dx;
        float y0f = floorf(py), x0f = floorf(pxs);
        float wy = py - y0f, wx = pxs - x0f;
        int y0 = (int)y0f, x0 = (int)x0f;
        int y1 = y0 + 1, x1 = x0 + 1;
        bool vy0 = (y0 >= 0) && (y0 < 64), vy1 = (y1 >= 0) && (y1 < 64);
        bool vx0 = (x0 >= 0) && (x0 < 64), vx1 = (x1 >= 0) && (x1 < 64);
        int cy0 = min(max(y0, 0), 63) + 3, cy1 = min(max(y1, 0), 63) + 3;
        int cx0 = min(max(x0, 0), 63) + 3, cx1 = min(max(x1, 0), 63) + 3;
        pw4[0][q] = (vy0 && vx0) ? (1.f - wy) * (1.f - wx) : 0.f;
        pw4[1][q] = (vy0 && vx1) ? (1.f - wy) * wx : 0.f;
        pw4[2][q] = (vy1 && vx0) ? wy * (1.f - wx) : 0.f;
        pw4[3][q] = (vy1 && vx1) ? wy * wx : 0.f;
        po4[q] = make_uchar4((unsigned char)(cy0 - R0), (unsigned char)(cy1 - R0),
                             (unsigned char)(cx0 - C0), (unsigned char)(cx1 - C0));
    }

    // sampling roles: thread = (pixel, 4-channel slice)
    int px_s = tid >> 5;    // 0..15
    int slice4 = tid & 31;  // 4 channels each
    // MFMA roles
    int wv = tid >> 6;
    int l = tid & 63;
    int col = l & 15, kg = l >> 4;

    f32x4 acc = (f32x4){0.f, 0.f, 0.f, 0.f};
    half8 wA8[4], wB8[4];

    auto BLEND = [&](int t, int buf) {
        int q = t * 16 + px_s;
        _Float16 w00 = (_Float16)pw4[0][q], w01 = (_Float16)pw4[1][q];
        _Float16 w10 = (_Float16)pw4[2][q], w11 = (_Float16)pw4[3][q];
        uchar4 pk = po4[q];
        int o0 = ((int)pk.x * COLSW) << 7;
        int o1 = ((int)pk.y * COLSW) << 7;
        int o2 = ((int)pk.z) << 7;
        int o3 = ((int)pk.w) << 7;
        int c0 = slice4 * 4;
        half4 a00 = *(const half4*)(win + o0 + o2 + c0);
        half4 a01 = *(const half4*)(win + o0 + o3 + c0);
        half4 a10 = *(const half4*)(win + o1 + o2 + c0);
        half4 a11 = *(const half4*)(win + o1 + o3 + c0);
        half4 r = a00 * w00 + a01 * w01 + a10 * w10 + a11 * w11;  // packed f16 fma
        *(half4*)&panel[buf][px_s][((slice4 >> 1) ^ (px_s & 7)) * 8 + (slice4 & 1) * 4] = r;
    };
    auto LOADW = [&](half8* w8, int t) {
        const half8* ap = (const half8*)wM + ((size_t)(t * 8 + wv) * 4) * 64 + l;
#pragma unroll
        for (int cc = 0; cc < 4; ++cc) w8[cc] = ap[cc * 64];
    };
    auto MM = [&](const half8* w8, int buf) {
#pragma unroll
        for (int cc = 0; cc < 4; ++cc) {
            half8 bf = *(const half8*)&panel[buf][col][((cc * 4 + kg) ^ (col & 7)) * 8];
            acc = __builtin_amdgcn_mfma_f32_16x16x32_f16(w8[cc], bf, acc, 0, 0, 0);
        }
    };
    auto BAR = [&]() {
        asm volatile("s_waitcnt lgkmcnt(0)" ::: "memory");
        __builtin_amdgcn_s_barrier();
        __builtin_amdgcn_sched_barrier(0);
    };

    // ---- prologue
    LOADW(wA8, 0);
    if (1 < T) LOADW(wB8, 1);
    BAR();  // window + params staged
    BLEND(0, 0);
    BAR();  // panel[0] ready

    for (int t = 0; t < T; t += 2) {
        MM(wA8, t & 1);
        if (t + 2 < T) LOADW(wA8, t + 2);
        if (t + 1 < T) BLEND(t + 1, (t + 1) & 1);
        BAR();
        if (t + 1 < T) {
            MM(wB8, (t + 1) & 1);
            if (t + 3 < T) LOADW(wB8, t + 3);
            if (t + 2 < T) BLEND(t + 2, (t + 2) & 1);
            BAR();
        }
    }

    // ---- fused epilogue: bias + gelu -> f16 CL
    int p = px0 + col;
    half4 t4;
#pragma unroll
    for (int r = 0; r < 4; ++r) {
        int oc = wv * 16 + kg * 4 + r;
        t4[r] = (_Float16)gelu_f(acc[r] * (1.0f / 16.0f) + bias[oc]);
    }
    if (OUTMODE == 0) {
        int h = p >> 6, w = p & 63;
        _Float16* dst = outH + (size_t)b * 70 * 72 * 128 +
                        ((size_t)(h + 3) * 72 + (3 + w)) * 128 + wv * 16 + kg * 4;
        *(half4*)dst = t4;
    } else {
        *(half4*)(outH + ((size_t)(b * HWSZ) + p) * 128 + wv * 16 + kg * 4) = t4;
    }
}

// ---------------- K6Z: z = gelu(a)*g fused with out = z @ w2 + b2
__global__ __launch_bounds__(256) void k6z(const _Float16* __restrict__ a5cl,
                                           const _Float16* __restrict__ gcl,
                                           const float* __restrict__ w2,
                                           const float* __restrict__ b2,
                                           float* __restrict__ out) {
    __shared__ float zs[16][128];
    int tid = threadIdx.x;
    int blk = blockIdx.x;  // 512: (b, 16-px group)
    int b = blk >> 8;
    int px0 = (blk & 255) << 4;
    int px = tid >> 4, sl = tid & 15;
    size_t rb = ((size_t)(b * HWSZ) + px0 + px) * 128 + sl * 8;
    half8 a = *(const half8*)(a5cl + rb);
    half8 g = *(const half8*)(gcl + rb);
#pragma unroll
    for (int j = 0; j < 8; ++j)
        zs[px][sl * 8 + j] = gelu_f((float)a[j]) * (float)g[j];
    __syncthreads();
    int d2 = (tid & 15) * 2;
    float acc0 = b2[d2], acc1 = b2[d2 + 1];
#pragma unroll 16
    for (int c = 0; c < 128; ++c) {
        float zv = zs[px][c];
        acc0 = fmaf(zv, w2[c * 32 + d2], acc0);
        acc1 = fmaf(zv, w2[c * 32 + d2 + 1], acc1);
    }
    float* o = out + ((size_t)(b * HWSZ) + px0 + px) * 32 + d2;
    o[0] = acc0;
    o[1] = acc1;
}

extern "C" void kernel_launch(void* const* d_in, const int* in_sizes, int n_in,
                              void* d_out, int out_size, void* d_ws, size_t ws_size,
                              hipStream_t stream) {
    const float* x   = (const float*)d_in[0];
    const float* w1  = (const float*)d_in[1];
    const float* b1  = (const float*)d_in[2];
    const float* dww = (const float*)d_in[3];
    const float* dwb = (const float*)d_in[4];
    const float* pww = (const float*)d_in[5];
    const float* pwb = (const float*)d_in[6];
    const float* o3w = (const float*)d_in[7];
    const float* o3b = (const float*)d_in[8];
    const float* d3w = (const float*)d_in[9];
    const float* d3b = (const float*)d_in[10];
    const float* o4w = (const float*)d_in[11];
    const float* o4b = (const float*)d_in[12];
    const float* d4w = (const float*)d_in[13];
    const float* d4b = (const float*)d_in[14];
    const float* o5w = (const float*)d_in[15];
    const float* o5b = (const float*)d_in[16];
    const float* d5w = (const float*)d_in[17];
    const float* d5b = (const float*)d_in[18];
    const float* w2  = (const float*)d_in[19];
    const float* b2  = (const float*)d_in[20];

    // ---- workspace map (float offsets) — unchanged
    float* ws = (float*)d_ws;
    float* offb = ws;                              // 1,048,576 fl
    _Float16* clA  = (_Float16*)(ws + 1048576);    // 645,120 fl (1,290,240 f16, B=2)
    _Float16* clB  = (_Float16*)(ws + 1693696);    // 645,120 fl (contiguous after clA)
    _Float16* xicl = (_Float16*)(ws + 2338816);    // 524,288 fl
    _Float16* dcl  = (_Float16*)(ws + 2863104);    // 524,288 fl
    _Float16* gcl  = (_Float16*)(ws + 3387392);    // 524,288 fl
    _Float16* a5cl = (_Float16*)(ws + 3911680);    // 524,288 fl
    _Float16* wA3  = (_Float16*)(ws + 4960256);    // 401,408 fl
    _Float16* wA4  = (_Float16*)(ws + 5361664);    // 18,432 fl
    _Float16* wA5  = (_Float16*)(ws + 5380096);    // 102,400 fl
    _Float16* wM3  = (_Float16*)(ws + 5482496);    // 401,408 fl
    _Float16* wM4  = (_Float16*)(ws + 5883904);    // 73,728 fl
    _Float16* wM5  = (_Float16*)(ws + 5957632);    // 102,400 fl
    _Float16* dwt  = (_Float16*)(ws + 6162432);    // 576 fl
    _Float16* pwt  = (_Float16*)(ws + 6163008);    // 16,384 fl
    _Float16* wA1  = (_Float16*)(ws + 9325120);    // 2,048 fl

    // prep
    kprep<<<14581, 256, 0, stream>>>(dww, pww, o3w, d3w, o4w, d4w, o5w, d5w, w1,
                                     dwt, pwt, wA3, wA4, wA5, wM3, wM4, wM5, wA1,
                                     (unsigned int*)clA);

    // front of net
    k1G<<<512, 512, 0, stream>>>(x, wA1, b1, xicl);
    k2_cl<<<512, 256, 0, stream>>>(xicl, dwt, dwb, dcl);
    k3G<<<dim3(512, 2), 512, 0, stream>>>(dcl, pwt, pwb, clA, gcl);

    // d3: k=7, pad=3, T=49  (k4 reverted to proven 256-block config)
    k4Gv4<7, 3, 49, 8, 1, 2, 32><<<256, 512, 0, stream>>>(clA, wA3, o3b, offb, 98);
    k5Gv14<7, 3, 49, 0><<<512, 512, 0, stream>>>(clA, offb, 128, wM3, d3b, clB);

    // d4: k=3, pad=1, T=9
    k4Gv4<3, 1, 9, 2, 4, 1, 64><<<128, 512, 0, stream>>>(clB, wA4, o4b, offb, 18);
    k5Gv14<3, 1, 9, 0><<<512, 512, 0, stream>>>(clB, offb, 32, wM4, d4b, clA);

    // d5: k=5, pad=2, T=25 -> flat CL f16
    k4Gv4<5, 2, 25, 4, 2, 1, 32><<<256, 512, 0, stream>>>(clA, wA5, o5b, offb, 50);
    k5Gv14<5, 2, 25, 2><<<512, 512, 0, stream>>>(clA, offb, 64, wM5, d5b, a5cl);

    // tail (fused)
    k6z<<<512, 256, 0, stream>>>(a5cl, gcl, w2, b2, (float*)d_out);
}